// Round 1
// baseline (2951.797 us; speedup 1.0000x reference)
//
#include <hip/hip_runtime.h>
#include <math.h>

#define Bn   256
#define Tn   128
#define HID  64
#define MCn  30

// ---------------------------------------------------------------------------
// softplus matching jax.nn.softplus numerics
__device__ __forceinline__ float softplusf_(float z) {
    return (z > 0.f) ? (z + log1pf(expf(-z))) : log1pf(expf(z));
}
__device__ __forceinline__ float sigmoidf_(float z) {
    return 1.0f / (1.0f + expf(-z));
}

// ---------------------------------------------------------------------------
// Prep kernel: per-sample LSTM gate constants, weight transposes, mask sum.
//   blocks 0..255   : gates_const[b][g] = b_ih[g]+b_hh[g] + sum_k m1[b][k]*W_ih[g][1+k]
//   block  256      : whhT4[k*256 + (r*64+j)] = W_hh[(r*64+j)*64 + k]
//   block  257      : invd = 1/sum(mask)
//   block  258      : W0T[(l*64+j)*32+kk] = fW0[(l*65 + 32*l + kk)*64 + j]; w0t
//   block  259      : W2a[(l*64+k)*64+i]  = fW2[(l*64+k)*128 + act_l + (i&31) + 64*(i>>5)]
extern "C" __global__ __launch_bounds__(256)
void prep_kernel(const int* __restrict__ marks, const float* __restrict__ mask,
                 const float* __restrict__ emb, const float* __restrict__ fW0,
                 const float* __restrict__ fW2, const float* __restrict__ W_ih,
                 const float* __restrict__ W_hh, const float* __restrict__ b_ih,
                 const float* __restrict__ b_hh,
                 float* __restrict__ gc, float* __restrict__ whhT4,
                 float* __restrict__ W0T, float* __restrict__ w0t,
                 float* __restrict__ W2a, float* __restrict__ invd)
{
    __shared__ float red[4];
    const int blk = blockIdx.x, tid = threadIdx.x;
    if (blk < Bn) {
        const int mark = marks[blk * Tn + 1];
        const float* er = emb + mark * HID;
        const float* wr = W_ih + tid * 65 + 1;
        float acc = b_ih[tid] + b_hh[tid];
        #pragma unroll
        for (int k = 0; k < HID; k++) acc += er[k] * wr[k];
        gc[blk * 256 + tid] = acc;
    } else if (blk == Bn) {
        for (int k = 0; k < 64; k++)
            whhT4[k * 256 + tid] = W_hh[tid * 64 + k];
    } else if (blk == Bn + 1) {
        float s = 0.f;
        for (int i = tid; i < Bn * Tn; i += 256) s += mask[i];
        #pragma unroll
        for (int off = 32; off >= 1; off >>= 1) s += __shfl_xor(s, off, 64);
        if ((tid & 63) == 0) red[tid >> 6] = s;
        __syncthreads();
        if (tid == 0) invd[0] = 1.0f / (red[0] + red[1] + red[2] + red[3]);
    } else if (blk == Bn + 2) {
        for (int i = tid; i < 2 * 64 * 32; i += 256) {
            int kk = i & 31, j = (i >> 5) & 63, l = i >> 11;
            W0T[i] = fW0[((l * 65) + 32 * l + kk) * 64 + j];
        }
        if (tid < 128) {
            int l = tid >> 6, j = tid & 63;
            w0t[tid] = fW0[((l * 65) + 64) * 64 + j];
        }
    } else {
        for (int idx = tid; idx < 2 * 64 * 64; idx += 256) {
            int i = idx & 63, k = (idx >> 6) & 63, l = idx >> 12;
            int act = 32 * (1 - l);
            W2a[idx] = fW2[(l * 64 + k) * 128 + act + (i & 31) + 64 * (i >> 5)];
        }
    }
}

// ---------------------------------------------------------------------------
// Sequential kernel: one wave = one batch element b; 128 time steps, no barriers.
// Lane j holds component j of h, c, x. Flow matvecs: lane j owns output column j,
// inputs broadcast via __shfl. Flow weights hoisted to VGPRs; W_hh staged in LDS.
extern "C" __global__ __launch_bounds__(64, 1)
void seq_kernel(const float* __restrict__ times, const float* __restrict__ mask,
                const float* __restrict__ fW0, const float* __restrict__ fb0,
                const float* __restrict__ fW1, const float* __restrict__ fb1,
                const float* __restrict__ fb2, const float* __restrict__ ftw,
                const float* __restrict__ Wi, const float* __restrict__ bi,
                const float* __restrict__ W_ih,
                const float* __restrict__ gc, const float* __restrict__ whhT4,
                const float* __restrict__ W2a, const float* __restrict__ invd,
                float* __restrict__ h_carry, float* __restrict__ out)
{
    const int j = threadIdx.x;      // lane 0..63
    const int b = blockIdx.x;       // batch element

    // ---- hoist per-lane weight columns into registers ----
    float w0c[2][32], w0tc[2], b0c[2], w1c[2][64], b1c[2], b2c[2], ftsc[2], ftsh[2];
    #pragma unroll
    for (int l = 0; l < 2; l++) {
        #pragma unroll
        for (int kk = 0; kk < 32; kk++)
            w0c[l][kk] = fW0[((l * 65) + 32 * l + kk) * 64 + j];
        w0tc[l] = fW0[((l * 65) + 64) * 64 + j];
        b0c[l]  = fb0[l * 64 + j];
        #pragma unroll
        for (int k = 0; k < 64; k++)
            w1c[l][k] = fW1[(l * 64 + k) * 64 + j];
        b1c[l] = fb1[l * 64 + j];
        const int act = 32 * (1 - l);
        b2c[l]  = fb2[l * 128 + act + (j & 31) + 64 * (j >> 5)];
        ftsc[l] = ftw[l * 128 + j];
        ftsh[l] = ftw[l * 128 + 64 + j];
    }
    const float wij = Wi[j];
    const float bi0 = bi[0];
    float wih0[4], gcr[4];
    #pragma unroll
    for (int r = 0; r < 4; r++) {
        wih0[r] = W_ih[(r * 64 + j) * 65];
        gcr[r]  = gc[b * 256 + r * 64 + j];
    }
    const float idn = invd[0];

    // ---- stage transposed W_hh in LDS (64 KB) ----
    __shared__ float whh[16384];
    for (int it = 0; it < 256; it++) whh[it * 64 + j] = whhT4[it * 64 + j];
    __syncthreads();

    float h = 0.f, c = 0.f, nllacc = 0.f;
    for (int t = 0; t < Tn; t++) {
        const float tb = times[b * Tn + t];
        h_carry[(b * Tn + t) * 64 + j] = h;   // carry at step START (for par kernel)

        // ---- flow(h, tb): 2 coupling layers ----
        float x = h;
        #pragma unroll
        for (int l = 0; l < 2; l++) {
            const int kb  = 32 * l;          // kept half base
            const int act = 32 * (1 - l);    // updated half base
            float acc = b0c[l] + tb * w0tc[l];
            #pragma unroll
            for (int kk = 0; kk < 32; kk++)
                acc += __shfl(x, kb + kk, 64) * w0c[l][kk];
            const float a1 = tanhf(acc);
            float acc2 = b1c[l];
            #pragma unroll
            for (int k = 0; k < 64; k++)
                acc2 += __shfl(a1, k, 64) * w1c[l][k];
            const float a2 = tanhf(acc2);
            // lane p computes ss for column act+(p&31), part p>>5 (0=scale,1=shift)
            float ss = b2c[l];
            #pragma unroll
            for (int k = 0; k < 64; k++)
                ss += __shfl(a2, k, 64) * W2a[(l * 64 + k) * 64 + j];
            const int src = (j - act) & 31;
            const float scl = __shfl(ss, src, 64);
            const float shf = __shfl(ss, 32 + src, 64);
            const float tsc = tanhf(tb * ftsc[l]);
            const float tsh = tanhf(tb * ftsh[l]);
            const float xa  = x * expf(scl * tsc) + shf * tsh;
            const bool active = (l == 0) ? (j >= 32) : (j < 32);
            x = active ? xa : x;
        }
        // h2 = x  -> hidden output
        out[1 + (b * Tn + t) * 64 + j] = x;

        // ---- lam = softplus(h2 . Wi + bi); accumulate -log(lam) ----
        float v = x * wij;
        #pragma unroll
        for (int off = 32; off >= 1; off >>= 1) v += __shfl_xor(v, off, 64);
        const float lam = softplusf_(v + bi0);
        nllacc += -logf(lam) * mask[b * Tn + t];

        // ---- LSTM update ----
        float g0 = gcr[0] + tb * wih0[0];
        float g1 = gcr[1] + tb * wih0[1];
        float g2 = gcr[2] + tb * wih0[2];
        float g3 = gcr[3] + tb * wih0[3];
        #pragma unroll 8
        for (int k = 0; k < 64; k++) {
            const float hk = __shfl(x, k, 64);
            g0 += hk * whh[k * 256 + j];
            g1 += hk * whh[k * 256 + 64 + j];
            g2 += hk * whh[k * 256 + 128 + j];
            g3 += hk * whh[k * 256 + 192 + j];
        }
        c = sigmoidf_(g1) * c + sigmoidf_(g0) * tanhf(g2);
        h = sigmoidf_(g3) * tanhf(c);
    }
    if (j == 0) atomicAdd(out, nllacc * idn);
}

// ---------------------------------------------------------------------------
// Parallel kernel: one THREAD = one (t,b,mc) flow sample. x[] in VGPRs;
// per-thread activation scratch in LDS (column-transposed: addr k*64+tid, so
// rolled k-loops are conflict-free). Weight rows are wave-uniform -> s_load
// stream, FMAs run at full VALU rate with SGPR operands.
extern "C" __global__ __launch_bounds__(64, 2)
void par_kernel(const float* __restrict__ times, const float* __restrict__ mask,
                const float* __restrict__ u,
                const float* __restrict__ fb0, const float* __restrict__ fW1,
                const float* __restrict__ fb1, const float* __restrict__ fb2,
                const float* __restrict__ ftw,
                const float* __restrict__ Wi, const float* __restrict__ bi,
                const float* __restrict__ W0T, const float* __restrict__ w0t,
                const float* __restrict__ W2a, const float* __restrict__ invd,
                const float* __restrict__ h_carry, float* __restrict__ out)
{
    const int tid = threadIdx.x;
    const int s   = blockIdx.x * 64 + tid;     // 0 .. 983039
    const int mc  = s % MCn;
    const int q   = s / MCn;                   // t*B + b
    const int b   = q & 255;
    const int t   = q >> 8;
    const float tb = times[b * Tn + t];
    const float ts = u[t * MCn + mc] * tb;     // flow time for this sample

    __shared__ float as_[64 * 64];             // activations, column tid

    float x[64];
    const float* hrow = h_carry + (b * Tn + t) * 64;
    #pragma unroll
    for (int k4 = 0; k4 < 16; k4++) {
        const float4 v = *(const float4*)(hrow + 4 * k4);
        x[4 * k4 + 0] = v.x; x[4 * k4 + 1] = v.y;
        x[4 * k4 + 2] = v.z; x[4 * k4 + 3] = v.w;
    }

    float acc[64];
    #pragma unroll
    for (int l = 0; l < 2; l++) {
        const int kb  = 32 * l;
        const int act = 32 * (1 - l);
        // mv1: 33-input matvec, j rolled, k unrolled over registers
        for (int j = 0; j < 64; j++) {
            const float* w = W0T + (l * 64 + j) * 32;
            float a = fb0[l * 64 + j] + ts * w0t[l * 64 + j];
            #pragma unroll
            for (int kk = 0; kk < 32; kk++) a += x[kb + kk] * w[kk];
            as_[j * 64 + tid] = tanhf(a);
        }
        // mv2: 64x64, k rolled, j unrolled into acc registers
        #pragma unroll
        for (int jj = 0; jj < 64; jj++) acc[jj] = fb1[l * 64 + jj];
        for (int k = 0; k < 64; k++) {
            const float ak = as_[k * 64 + tid];
            const float* w = fW1 + (l * 64 + k) * 64;
            #pragma unroll
            for (int jj = 0; jj < 64; jj++) acc[jj] += ak * w[jj];
        }
        #pragma unroll
        for (int jj = 0; jj < 64; jj++) as_[jj * 64 + tid] = tanhf(acc[jj]);
        // mv3: only the 64 consumed scale/shift columns
        #pragma unroll
        for (int i = 0; i < 64; i++)
            acc[i] = fb2[l * 128 + act + (i & 31) + 64 * (i >> 5)];
        for (int k = 0; k < 64; k++) {
            const float ak = as_[k * 64 + tid];
            const float* w = W2a + (l * 64 + k) * 64;
            #pragma unroll
            for (int i = 0; i < 64; i++) acc[i] += ak * w[i];
        }
        // coupling update on active half
        #pragma unroll
        for (int i = 0; i < 32; i++) {
            const int jj = act + i;
            const float tsc = tanhf(ts * ftw[l * 128 + jj]);
            const float tsh = tanhf(ts * ftw[l * 128 + 64 + jj]);
            x[jj] = x[jj] * expf(acc[i] * tsc) + acc[32 + i] * tsh;
        }
    }
    // intensity + loss contribution
    float d = bi[0];
    #pragma unroll
    for (int k = 0; k < 64; k++) d += x[k] * Wi[k];
    const float sp = softplusf_(d);
    float contrib = sp * tb * (1.0f / MCn) * invd[0] * mask[b * Tn + t];
    #pragma unroll
    for (int off = 32; off >= 1; off >>= 1) contrib += __shfl_xor(contrib, off, 64);
    if (tid == 0) atomicAdd(out, contrib);
}

// ---------------------------------------------------------------------------
extern "C" void kernel_launch(void* const* d_in, const int* in_sizes, int n_in,
                              void* d_out, int out_size, void* d_ws, size_t ws_size,
                              hipStream_t stream)
{
    const float* times = (const float*)d_in[0];
    const int*   marks = (const int*)  d_in[1];
    const float* mask  = (const float*)d_in[2];
    const float* u     = (const float*)d_in[3];
    const float* emb   = (const float*)d_in[4];
    const float* fW0   = (const float*)d_in[5];
    const float* fb0   = (const float*)d_in[6];
    const float* fW1   = (const float*)d_in[7];
    const float* fb1   = (const float*)d_in[8];
    const float* fW2   = (const float*)d_in[9];
    const float* fb2   = (const float*)d_in[10];
    const float* ftw   = (const float*)d_in[11];
    const float* Wi    = (const float*)d_in[12];
    const float* bi    = (const float*)d_in[13];
    const float* W_ih  = (const float*)d_in[14];
    const float* W_hh  = (const float*)d_in[15];
    const float* b_ih  = (const float*)d_in[16];
    const float* b_hh  = (const float*)d_in[17];
    float* out = (float*)d_out;

    float* w       = (float*)d_ws;
    float* h_carry = w;                    // B*T*64 = 2097152
    float* gc      = h_carry + 2097152;    // B*256  = 65536
    float* whhT4   = gc + 65536;           // 16384
    float* W0T     = whhT4 + 16384;        // 4096
    float* w0t     = W0T + 4096;           // 128
    float* W2a     = w0t + 128;            // 8192
    float* invd    = W2a + 8192;           // 1

    hipMemsetAsync(d_out, 0, sizeof(float), stream);   // zero the loss slot

    prep_kernel<<<260, 256, 0, stream>>>(marks, mask, emb, fW0, fW2, W_ih, W_hh,
                                         b_ih, b_hh, gc, whhT4, W0T, w0t, W2a, invd);
    seq_kernel<<<Bn, 64, 0, stream>>>(times, mask, fW0, fb0, fW1, fb1, fb2, ftw,
                                      Wi, bi, W_ih, gc, whhT4, W2a, invd,
                                      h_carry, out);
    par_kernel<<<(Bn * Tn * MCn) / 64, 64, 0, stream>>>(times, mask, u, fb0, fW1,
                                                        fb1, fb2, ftw, Wi, bi,
                                                        W0T, w0t, W2a, invd,
                                                        h_carry, out);
}

// Round 2
// 1623.476 us; speedup vs baseline: 1.8182x; 1.8182x over previous
//
#include <hip/hip_runtime.h>
#include <math.h>

#define Bn   256
#define Tn   128
#define HID  64
#define MCn  30

// ---------------------------------------------------------------------------
// fast transcendentals (v_exp_f32 / v_rcp_f32 based, ~2-3 ulp)
__device__ __forceinline__ float rcp_(float x) { return __builtin_amdgcn_rcpf(x); }
__device__ __forceinline__ float tanhf_(float x) {
    float xx = fminf(fmaxf(x, -9.0f), 9.0f);
    float e  = __expf(2.0f * xx);
    return (e - 1.0f) * rcp_(e + 1.0f);
}
__device__ __forceinline__ float sigmoidf_(float x) {
    return rcp_(1.0f + __expf(-x));
}
__device__ __forceinline__ float softplusf_(float z) {
    float e = __expf(-fabsf(z));
    return fmaxf(z, 0.0f) + __logf(1.0f + e);
}

// ---------------------------------------------------------------------------
// Prep kernel.
//   blocks 0..255 : gc[b][g] = b_ih[g]+b_hh[g] + sum_k m1[b][k]*W_ih[g][1+k]
//   block  256    : whhlg[j*260 + k*4 + r] = W_hh[(r*64+j)*64 + k]   (stride 260: 16B-aligned, 4 mod 32)
//   block  257    : invd = 1/sum(mask)
//   block  258    : W0T / w0t   (par kernel layouts)
//   block  259    : W2a         (par kernel layout)
//   block  260    : w2lg[l*4352 + j*68 + k] = fW2[(l*64+k)*128 + act_l + (j&31) + 64*(j>>5)]
extern "C" __global__ __launch_bounds__(256)
void prep_kernel(const int* __restrict__ marks, const float* __restrict__ mask,
                 const float* __restrict__ emb, const float* __restrict__ fW0,
                 const float* __restrict__ fW2, const float* __restrict__ W_ih,
                 const float* __restrict__ W_hh, const float* __restrict__ b_ih,
                 const float* __restrict__ b_hh,
                 float* __restrict__ gc, float* __restrict__ whhlg,
                 float* __restrict__ W0T, float* __restrict__ w0t,
                 float* __restrict__ W2a, float* __restrict__ w2lg,
                 float* __restrict__ invd)
{
    __shared__ float red[4];
    const int blk = blockIdx.x, tid = threadIdx.x;
    if (blk < Bn) {
        const int mark = marks[blk * Tn + 1];
        const float* er = emb + mark * HID;
        const float* wr = W_ih + tid * 65 + 1;
        float acc = b_ih[tid] + b_hh[tid];
        #pragma unroll
        for (int k = 0; k < HID; k++) acc += er[k] * wr[k];
        gc[blk * 256 + tid] = acc;
    } else if (blk == Bn) {
        for (int idx = tid; idx < 64 * 64 * 4; idx += 256) {
            int j = idx >> 8, k = (idx >> 2) & 63, r = idx & 3;
            whhlg[j * 260 + k * 4 + r] = W_hh[(r * 64 + j) * 64 + k];
        }
    } else if (blk == Bn + 1) {
        float s = 0.f;
        for (int i = tid; i < Bn * Tn; i += 256) s += mask[i];
        #pragma unroll
        for (int off = 32; off >= 1; off >>= 1) s += __shfl_xor(s, off, 64);
        if ((tid & 63) == 0) red[tid >> 6] = s;
        __syncthreads();
        if (tid == 0) invd[0] = 1.0f / (red[0] + red[1] + red[2] + red[3]);
    } else if (blk == Bn + 2) {
        for (int i = tid; i < 2 * 64 * 32; i += 256) {
            int kk = i & 31, j = (i >> 5) & 63, l = i >> 11;
            W0T[i] = fW0[((l * 65) + 32 * l + kk) * 64 + j];
        }
        if (tid < 128) {
            int l = tid >> 6, j = tid & 63;
            w0t[tid] = fW0[((l * 65) + 64) * 64 + j];
        }
    } else if (blk == Bn + 3) {
        for (int idx = tid; idx < 2 * 64 * 64; idx += 256) {
            int i = idx & 63, k = (idx >> 6) & 63, l = idx >> 12;
            int act = 32 * (1 - l);
            W2a[idx] = fW2[(l * 64 + k) * 128 + act + (i & 31) + 64 * (i >> 5)];
        }
    } else {
        for (int idx = tid; idx < 2 * 64 * 64; idx += 256) {
            int k = idx & 63, j = (idx >> 6) & 63, l = idx >> 12;
            int act = 32 * (1 - l);
            w2lg[l * 4352 + j * 68 + k] =
                fW2[(l * 64 + k) * 128 + act + (j & 31) + 64 * (j >> 5)];
        }
    }
}

// ---------------------------------------------------------------------------
// Sequential kernel: one wave = one batch element. NO cross-lane shuffles in
// the matvecs: vectors round-trip through small LDS buffers (1 ds_write per
// lane, then uniform-address ds_read_b128 broadcasts). Per-lane weight streams
// (W_hh, fW2 columns) live in LDS with row strides 260/68 (=4 mod 32: optimal
// 8-group bank spread for b128). 102 KB dynamic LDS.
extern "C" __global__ __launch_bounds__(64, 1)
void seq_kernel(const float* __restrict__ times, const float* __restrict__ mask,
                const float* __restrict__ fW0, const float* __restrict__ fb0,
                const float* __restrict__ fW1, const float* __restrict__ fb1,
                const float* __restrict__ fb2, const float* __restrict__ ftw,
                const float* __restrict__ Wi, const float* __restrict__ bi,
                const float* __restrict__ W_ih,
                const float* __restrict__ gc, const float* __restrict__ w2lg,
                const float* __restrict__ whhlg, const float* __restrict__ invd,
                float* __restrict__ h_carry, float* __restrict__ out)
{
    const int j = threadIdx.x;
    const int b = blockIdx.x;

    extern __shared__ float smem[];
    float* w2l  = smem;            // 2*64*68  = 8704 floats
    float* whhl = smem + 8704;     // 64*260   = 16640 floats
    float* xl   = smem + 25344;    // 64
    float* al   = smem + 25408;    // 64
    float* ssl  = smem + 25472;    // 64

    // ---- per-lane weight columns in registers ----
    float w0c[2][32], w0tc[2], b0c[2], w1c[2][64], b1c[2], b2c[2], ftsc[2], ftsh[2];
    #pragma unroll
    for (int l = 0; l < 2; l++) {
        #pragma unroll
        for (int kk = 0; kk < 32; kk++)
            w0c[l][kk] = fW0[((l * 65) + 32 * l + kk) * 64 + j];
        w0tc[l] = fW0[((l * 65) + 64) * 64 + j];
        b0c[l]  = fb0[l * 64 + j];
        #pragma unroll
        for (int k = 0; k < 64; k++)
            w1c[l][k] = fW1[(l * 64 + k) * 64 + j];
        b1c[l] = fb1[l * 64 + j];
        const int act = 32 * (1 - l);
        b2c[l]  = fb2[l * 128 + act + (j & 31) + 64 * (j >> 5)];
        ftsc[l] = ftw[l * 128 + j];
        ftsh[l] = ftw[l * 128 + 64 + j];
    }
    const float wij = Wi[j];
    const float bi0 = bi[0];
    float wih0[4], gcr[4];
    #pragma unroll
    for (int r = 0; r < 4; r++) {
        wih0[r] = W_ih[(r * 64 + j) * 65];
        gcr[r]  = gc[b * 256 + r * 64 + j];
    }
    const float idn = invd[0];

    // ---- stage weight streams into LDS (coalesced float4 copies) ----
    {
        const float4* s1 = (const float4*)w2lg;  float4* d1 = (float4*)w2l;
        for (int i = j; i < 2176; i += 64) d1[i] = s1[i];
        const float4* s2 = (const float4*)whhlg; float4* d2 = (float4*)whhl;
        for (int i = j; i < 4160; i += 64) d2[i] = s2[i];
    }
    __syncthreads();

    float h = 0.f, c = 0.f, nllacc = 0.f;
    for (int t = 0; t < Tn; t++) {
        const float tb = times[b * Tn + t];
        h_carry[(b * Tn + t) * 64 + j] = h;
        float x = h;
        xl[j] = x;
        #pragma unroll
        for (int l = 0; l < 2; l++) {
            const int kb  = 32 * l;
            const int act = 32 * (1 - l);
            // mv1: kept half (broadcast) x per-lane register weights
            float p0 = b0c[l] + tb * w0tc[l], p1 = 0.f, p2 = 0.f, p3 = 0.f;
            #pragma unroll
            for (int k4 = 0; k4 < 8; k4++) {
                const float4 xv = *(const float4*)(xl + kb + 4 * k4);
                p0 += xv.x * w0c[l][4 * k4 + 0];
                p1 += xv.y * w0c[l][4 * k4 + 1];
                p2 += xv.z * w0c[l][4 * k4 + 2];
                p3 += xv.w * w0c[l][4 * k4 + 3];
            }
            const float a1 = tanhf_((p0 + p1) + (p2 + p3));
            al[j] = a1;
            // mv2: 64x64, broadcast a1 x register weights
            p0 = b1c[l]; p1 = p2 = p3 = 0.f;
            #pragma unroll
            for (int k4 = 0; k4 < 16; k4++) {
                const float4 av = *(const float4*)(al + 4 * k4);
                p0 += av.x * w1c[l][4 * k4 + 0];
                p1 += av.y * w1c[l][4 * k4 + 1];
                p2 += av.z * w1c[l][4 * k4 + 2];
                p3 += av.w * w1c[l][4 * k4 + 3];
            }
            const float a2 = tanhf_((p0 + p1) + (p2 + p3));
            al[j] = a2;   // in-order DS: all mv2 reads precede this write
            // mv3: broadcast a2 x LDS weight column (b128, 8-group spread)
            p0 = b2c[l]; p1 = p2 = p3 = 0.f;
            const float* w2p = w2l + l * 4352 + j * 68;
            #pragma unroll
            for (int k4 = 0; k4 < 16; k4++) {
                const float4 av = *(const float4*)(al + 4 * k4);
                const float4 wv = *(const float4*)(w2p + 4 * k4);
                p0 += av.x * wv.x;
                p1 += av.y * wv.y;
                p2 += av.z * wv.z;
                p3 += av.w * wv.w;
            }
            const float ss = (p0 + p1) + (p2 + p3);
            ssl[j] = ss;
            // coupling update
            const int idx = (j - act) & 31;
            const float scl = ssl[idx];
            const float shf = ssl[idx + 32];
            const float tsc = tanhf_(tb * ftsc[l]);
            const float tsh = tanhf_(tb * ftsh[l]);
            const float xa  = x * __expf(scl * tsc) + shf * tsh;
            const bool active = (l == 0) ? (j >= 32) : (j < 32);
            x = active ? xa : x;
            xl[j] = x;
        }
        // hidden output (h2 = x)
        out[1 + (b * Tn + t) * 64 + j] = x;

        // lam = softplus(h2 . Wi + bi)
        float v = x * wij;
        #pragma unroll
        for (int off = 32; off >= 1; off >>= 1) v += __shfl_xor(v, off, 64);
        const float lam = softplusf_(v + bi0);
        nllacc += -__logf(lam) * mask[b * Tn + t];

        // LSTM: lane j owns gate outputs r*64+j; weights from LDS b128 stream
        float g0 = gcr[0] + tb * wih0[0];
        float g1 = gcr[1] + tb * wih0[1];
        float g2 = gcr[2] + tb * wih0[2];
        float g3 = gcr[3] + tb * wih0[3];
        const float* wr_base = whhl + j * 260;
        #pragma unroll
        for (int k4 = 0; k4 < 16; k4++) {
            const float4 hv = *(const float4*)(xl + 4 * k4);
            const float* wr = wr_base + 16 * k4;
            const float4 wa = *(const float4*)(wr);
            const float4 wb = *(const float4*)(wr + 4);
            const float4 wc = *(const float4*)(wr + 8);
            const float4 wd = *(const float4*)(wr + 12);
            g0 += hv.x * wa.x; g1 += hv.x * wa.y; g2 += hv.x * wa.z; g3 += hv.x * wa.w;
            g0 += hv.y * wb.x; g1 += hv.y * wb.y; g2 += hv.y * wb.z; g3 += hv.y * wb.w;
            g0 += hv.z * wc.x; g1 += hv.z * wc.y; g2 += hv.z * wc.z; g3 += hv.z * wc.w;
            g0 += hv.w * wd.x; g1 += hv.w * wd.y; g2 += hv.w * wd.z; g3 += hv.w * wd.w;
        }
        c = sigmoidf_(g1) * c + sigmoidf_(g0) * tanhf_(g2);
        h = sigmoidf_(g3) * tanhf_(c);
    }
    if (j == 0) atomicAdd(out, nllacc * idn);
}

// ---------------------------------------------------------------------------
// Parallel kernel: one thread = one (t,b,mc) flow sample.
extern "C" __global__ __launch_bounds__(64, 2)
void par_kernel(const float* __restrict__ times, const float* __restrict__ mask,
                const float* __restrict__ u,
                const float* __restrict__ fb0, const float* __restrict__ fW1,
                const float* __restrict__ fb1, const float* __restrict__ fb2,
                const float* __restrict__ ftw,
                const float* __restrict__ Wi, const float* __restrict__ bi,
                const float* __restrict__ W0T, const float* __restrict__ w0t,
                const float* __restrict__ W2a, const float* __restrict__ invd,
                const float* __restrict__ h_carry, float* __restrict__ out)
{
    const int tid = threadIdx.x;
    const int s   = blockIdx.x * 64 + tid;
    const int mc  = s % MCn;
    const int q   = s / MCn;
    const int b   = q & 255;
    const int t   = q >> 8;
    const float tb = times[b * Tn + t];
    const float ts = u[t * MCn + mc] * tb;

    __shared__ float as_[64 * 64];

    float x[64];
    const float* hrow = h_carry + (b * Tn + t) * 64;
    #pragma unroll
    for (int k4 = 0; k4 < 16; k4++) {
        const float4 v = *(const float4*)(hrow + 4 * k4);
        x[4 * k4 + 0] = v.x; x[4 * k4 + 1] = v.y;
        x[4 * k4 + 2] = v.z; x[4 * k4 + 3] = v.w;
    }

    float acc[64];
    #pragma unroll
    for (int l = 0; l < 2; l++) {
        const int kb  = 32 * l;
        const int act = 32 * (1 - l);
        // mv1: 4-way split accumulators to shorten the dependent chain
        for (int jj = 0; jj < 64; jj++) {
            const float* w = W0T + (l * 64 + jj) * 32;
            float s0 = fb0[l * 64 + jj] + ts * w0t[l * 64 + jj];
            float s1 = 0.f, s2 = 0.f, s3 = 0.f;
            #pragma unroll
            for (int kk = 0; kk < 32; kk += 4) {
                s0 += x[kb + kk + 0] * w[kk + 0];
                s1 += x[kb + kk + 1] * w[kk + 1];
                s2 += x[kb + kk + 2] * w[kk + 2];
                s3 += x[kb + kk + 3] * w[kk + 3];
            }
            as_[jj * 64 + tid] = tanhf_((s0 + s1) + (s2 + s3));
        }
        // mv2
        #pragma unroll
        for (int jj = 0; jj < 64; jj++) acc[jj] = fb1[l * 64 + jj];
        #pragma unroll 4
        for (int k = 0; k < 64; k++) {
            const float ak = as_[k * 64 + tid];
            const float* w = fW1 + (l * 64 + k) * 64;
            #pragma unroll
            for (int jj = 0; jj < 64; jj++) acc[jj] += ak * w[jj];
        }
        #pragma unroll
        for (int jj = 0; jj < 64; jj++) as_[jj * 64 + tid] = tanhf_(acc[jj]);
        // mv3
        #pragma unroll
        for (int i = 0; i < 64; i++)
            acc[i] = fb2[l * 128 + act + (i & 31) + 64 * (i >> 5)];
        #pragma unroll 4
        for (int k = 0; k < 64; k++) {
            const float ak = as_[k * 64 + tid];
            const float* w = W2a + (l * 64 + k) * 64;
            #pragma unroll
            for (int i = 0; i < 64; i++) acc[i] += ak * w[i];
        }
        // coupling update
        #pragma unroll
        for (int i = 0; i < 32; i++) {
            const int jj = act + i;
            const float tsc = tanhf_(ts * ftw[l * 128 + jj]);
            const float tsh = tanhf_(ts * ftw[l * 128 + 64 + jj]);
            x[jj] = x[jj] * __expf(acc[i] * tsc) + acc[32 + i] * tsh;
        }
    }
    // intensity + loss contribution
    float d0 = bi[0], d1 = 0.f, d2 = 0.f, d3 = 0.f;
    #pragma unroll
    for (int k = 0; k < 64; k += 4) {
        d0 += x[k + 0] * Wi[k + 0];
        d1 += x[k + 1] * Wi[k + 1];
        d2 += x[k + 2] * Wi[k + 2];
        d3 += x[k + 3] * Wi[k + 3];
    }
    const float sp = softplusf_((d0 + d1) + (d2 + d3));
    float contrib = sp * tb * (1.0f / MCn) * invd[0] * mask[b * Tn + t];
    #pragma unroll
    for (int off = 32; off >= 1; off >>= 1) contrib += __shfl_xor(contrib, off, 64);
    if (tid == 0) atomicAdd(out, contrib);
}

// ---------------------------------------------------------------------------
extern "C" void kernel_launch(void* const* d_in, const int* in_sizes, int n_in,
                              void* d_out, int out_size, void* d_ws, size_t ws_size,
                              hipStream_t stream)
{
    const float* times = (const float*)d_in[0];
    const int*   marks = (const int*)  d_in[1];
    const float* mask  = (const float*)d_in[2];
    const float* u     = (const float*)d_in[3];
    const float* emb   = (const float*)d_in[4];
    const float* fW0   = (const float*)d_in[5];
    const float* fb0   = (const float*)d_in[6];
    const float* fW1   = (const float*)d_in[7];
    const float* fb1   = (const float*)d_in[8];
    const float* fW2   = (const float*)d_in[9];
    const float* fb2   = (const float*)d_in[10];
    const float* ftw   = (const float*)d_in[11];
    const float* Wi    = (const float*)d_in[12];
    const float* bi    = (const float*)d_in[13];
    const float* W_ih  = (const float*)d_in[14];
    const float* W_hh  = (const float*)d_in[15];
    const float* b_ih  = (const float*)d_in[16];
    const float* b_hh  = (const float*)d_in[17];
    float* out = (float*)d_out;

    float* w       = (float*)d_ws;
    float* h_carry = w;                    // 2097152
    float* gc      = h_carry + 2097152;    // 65536
    float* W0T     = gc + 65536;           // 4096
    float* w0t     = W0T + 4096;           // 128
    float* W2a     = w0t + 128;            // 8192
    float* invd    = W2a + 8192;           // 4 (padded)
    float* w2lg    = invd + 4;             // 8704
    float* whhlg   = w2lg + 8704;          // 16640

    hipMemsetAsync(d_out, 0, sizeof(float), stream);

    const int SEQ_SMEM = 25536 * 4;  // 102144 B dynamic LDS
    hipFuncSetAttribute((const void*)seq_kernel,
                        hipFuncAttributeMaxDynamicSharedMemorySize, SEQ_SMEM);

    prep_kernel<<<261, 256, 0, stream>>>(marks, mask, emb, fW0, fW2, W_ih, W_hh,
                                         b_ih, b_hh, gc, whhlg, W0T, w0t, W2a,
                                         w2lg, invd);
    seq_kernel<<<Bn, 64, SEQ_SMEM, stream>>>(times, mask, fW0, fb0, fW1, fb1,
                                             fb2, ftw, Wi, bi, W_ih, gc, w2lg,
                                             whhlg, invd, h_carry, out);
    par_kernel<<<(Bn * Tn * MCn) / 64, 64, 0, stream>>>(times, mask, u, fb0, fW1,
                                                        fb1, fb2, ftw, Wi, bi,
                                                        W0T, w0t, W2a, invd,
                                                        h_carry, out);
}